// Round 6
// baseline (118.972 us; speedup 1.0000x reference)
//
#include <hip/hip_runtime.h>

#define HW 2304          // 48*48
#define HW4 576          // HW/4
#define PART_STRIDE 2308 // 2304 A-partials + 1 sq, padded to mult of 4
#define R2 8             // second-level row groups
#define S1_T 512         // stage-1 threads (8 waves); 4 blocks/CU = 32 waves/CU

// Stage 1 (v6): 1024 blocks x 512 threads = EXACTLY 4 blocks/CU on 256 CUs,
// zero dispatch tail, 32 waves/CU (rounds 2-5 never exceeded ~56% occ; BW
// tracked occupancy, so this is the isolated lever). Each block sweeps a
// contiguous 8-batch slab = 9 chunks of 512 float4. Phase of chunk c is
// (512c) mod 576 (period 9) -> each thread hits 9 known hw positions once,
// accumulated via fire-and-forget ds_add_f32 into component-major As[4][576]
// (lanes -> consecutive banks, 2-way aliasing = free; non-returning atomics
// never stall the wave).
__global__ __launch_bounds__(S1_T, 8) void sc_stage1(
    const float4* __restrict__ out4, const float4* __restrict__ tgt4,
    float* __restrict__ part, int N4, int G)
{
    __shared__ float As[4][HW4];
    __shared__ float wsum[8];
    int tid = threadIdx.x;
    int blk = blockIdx.x;

    for (int k = tid; k < 4 * HW4; k += S1_T) (&As[0][0])[k] = 0.f;
    __syncthreads();

    const int OFF[9] = {0, 512, 448, 384, 320, 256, 192, 128, 64};
    float sq = 0.f;
    size_t span = (size_t)G * 9 * S1_T;        // float4 per block
    size_t base = (size_t)blk * span + tid;
    bool full = (size_t)(blk + 1) * span <= (size_t)N4;

    if (full) {
        for (int g = 0; g < G; ++g) {
            #pragma unroll
            for (int c = 0; c < 9; ++c) {
                size_t i = base + ((size_t)g * 9 + c) * S1_T;
                float4 o = out4[i];
                float4 t = tgt4[i];
                float d0 = o.x - t.x, d1 = o.y - t.y,
                      d2 = o.z - t.z, d3 = o.w - t.w;
                sq = fmaf(d0, d0, sq); sq = fmaf(d1, d1, sq);
                sq = fmaf(d2, d2, sq); sq = fmaf(d3, d3, sq);
                int p = tid + OFF[c]; if (p >= HW4) p -= HW4;
                atomicAdd(&As[0][p], fabsf(d0));
                atomicAdd(&As[1][p], fabsf(d1));
                atomicAdd(&As[2][p], fabsf(d2));
                atomicAdd(&As[3][p], fabsf(d3));
            }
        }
    } else {
        for (int g = 0; g < G; ++g) {
            #pragma unroll
            for (int c = 0; c < 9; ++c) {
                size_t i = base + ((size_t)g * 9 + c) * S1_T;
                if (i < (size_t)N4) {
                    float4 o = out4[i];
                    float4 t = tgt4[i];
                    float d0 = o.x - t.x, d1 = o.y - t.y,
                          d2 = o.z - t.z, d3 = o.w - t.w;
                    sq = fmaf(d0, d0, sq); sq = fmaf(d1, d1, sq);
                    sq = fmaf(d2, d2, sq); sq = fmaf(d3, d3, sq);
                    int p = tid + OFF[c]; if (p >= HW4) p -= HW4;
                    atomicAdd(&As[0][p], fabsf(d0));
                    atomicAdd(&As[1][p], fabsf(d1));
                    atomicAdd(&As[2][p], fabsf(d2));
                    atomicAdd(&As[3][p], fabsf(d3));
                }
            }
        }
    }
    __syncthreads();

    // writeback LDS partial -> part row (hw = 4*p + comp  <->  As[comp][p])
    float* pbase = part + (size_t)blk * PART_STRIDE;
    for (int k = tid; k < HW; k += S1_T)
        pbase[k] = As[k & 3][k >> 2];

    // block-reduce sq (8 waves)
    #pragma unroll
    for (int off = 32; off; off >>= 1) sq += __shfl_down(sq, off);
    if ((tid & 63) == 0) wsum[tid >> 6] = sq;
    __syncthreads();
    if (tid == 0) {
        float s = 0.f;
        #pragma unroll
        for (int w = 0; w < 8; ++w) s += wsum[w];
        pbase[HW] = s;
    }
}

// Stage 2: 36 column-blocks x R2 row-groups + 1 = 289 blocks x 256.
// Block (c,r) reduces rows k == r (mod R2) for 64 columns -> part2[r][hw]
// (un-normalized; works for any NB). Block 288 reduces the sq partials ->
// MSE into out[0] (plain store: idempotent across graph replays).
__global__ __launch_bounds__(256) void sc_stage2(
    const float* __restrict__ part, float* __restrict__ part2,
    float* __restrict__ out, int NB, float invN)
{
    __shared__ float red[4][64];
    int blk  = blockIdx.x;
    int lane = threadIdx.x & 63;
    int grp  = threadIdx.x >> 6;   // 0..3
    if (blk < 36 * R2) {
        int c = blk / R2, r = blk % R2;
        int hw = c * 64 + lane;          // coalesced per wave
        float s = 0.f;
        for (int k = r + grp * R2; k < NB; k += 4 * R2)
            s += part[(size_t)k * PART_STRIDE + hw];
        red[grp][lane] = s;
        __syncthreads();
        if (grp == 0)
            part2[r * HW + hw] = red[0][lane] + red[1][lane] +
                                 red[2][lane] + red[3][lane];
    } else {
        float s = 0.f;
        for (int k = threadIdx.x; k < NB; k += 256)
            s += part[(size_t)k * PART_STRIDE + HW];
        #pragma unroll
        for (int off = 32; off; off >>= 1) s += __shfl_down(s, off);
        if (lane == 0) red[0][grp] = s;
        __syncthreads();
        if (threadIdx.x == 0)
            out[0] = (red[0][0] + red[0][1] + red[0][2] + red[0][3]) * invN;
    }
}

// Stage 3: one block per (i,j). A[hw] folded in on the fly from part2
// (8 x 2304 floats, L2-hot). out += 0.5*mu*l1^2 (54 atomic adds;
// fp ordering noise ~1e-7 << threshold).
__global__ __launch_bounds__(256) void sc_stage3(
    const float* __restrict__ part2, const float* __restrict__ psu,
    const float* __restrict__ mu, float* __restrict__ out, float invB)
{
    int j = blockIdx.x;
    int tid = threadIdx.x;
    const float* p = psu + (size_t)j * HW;
    float s = 0.f;
    for (int hw = tid; hw < HW; hw += 256) {
        float a = 0.f;
        #pragma unroll
        for (int r = 0; r < R2; ++r) a += part2[r * HW + hw];
        s += a * fabsf(p[hw]);
    }
    #pragma unroll
    for (int off = 32; off; off >>= 1) s += __shfl_down(s, off);
    __shared__ float wsum[4];
    if ((tid & 63) == 0) wsum[tid >> 6] = s;
    __syncthreads();
    if (tid == 0) {
        float l1 = (wsum[0] + wsum[1] + wsum[2] + wsum[3]) * invB * (1.0f / HW);
        float contrib = 0.5f * mu[j] * l1 * l1;   // GAMMA = 1
        atomicAdd(out, contrib);
    }
}

extern "C" void kernel_launch(void* const* d_in, const int* in_sizes, int n_in,
                              void* d_out, int out_size, void* d_ws, size_t ws_size,
                              hipStream_t stream)
{
    const float* outp = (const float*)d_in[0];
    const float* tgtp = (const float*)d_in[1];
    const float* psu  = (const float*)d_in[2];
    const float* mu   = (const float*)d_in[3];

    int B   = in_sizes[0] / HW;     // 8192
    int nij = in_sizes[3];          // 54
    int N4  = in_sizes[0] / 4;      // total float4 count (B*HW4)

    // NB blocks, each covering G*9*512 float4. B=8192 -> NB=1024, G=1.
    int G  = 1;
    int NB = (N4 + 9 * S1_T - 1) / (9 * S1_T);
    while (NB > 64 &&
           ((size_t)NB * PART_STRIDE + (size_t)R2 * HW) * sizeof(float) > ws_size) {
        G <<= 1;
        int span = G * 9 * S1_T;
        NB = (N4 + span - 1) / span;
    }

    float* part  = (float*)d_ws;
    float* part2 = part + (size_t)NB * PART_STRIDE;
    float invN   = 1.0f / ((float)B * (float)HW);
    float invB   = 1.0f / (float)B;

    sc_stage1<<<NB, S1_T, 0, stream>>>((const float4*)outp, (const float4*)tgtp,
                                       part, N4, G);
    sc_stage2<<<36 * R2 + 1, 256, 0, stream>>>(part, part2, (float*)d_out,
                                               NB, invN);
    sc_stage3<<<nij, 256, 0, stream>>>(part2, psu, mu, (float*)d_out, invB);
}

// Round 7
// 43.609 us; speedup vs baseline: 2.7281x; 2.7281x over previous
//
#include <hip/hip_runtime.h>

#define HW 2304          // 48*48
#define HW4 576          // HW/4
#define PART_STRIDE 2308 // 2304 A-partials + 1 sq, padded to mult of 4

typedef float __attribute__((ext_vector_type(4))) f32x4;

// Stage 1 (v7): R2's phase-locked geometry (576 threads = one float4 column
// per thread, register accumulators, NB=512 -> 16 batches/block, zero tail)
// with the inner loop as ONE inline-asm block issuing 8 global_load_dwordx4
// (SADDR form: 8 uniform SGPR bases, shared per-lane voffset) then
// s_waitcnt vmcnt(0). Guarantees 8x16B in flight per thread -- the compiler
// register-minimized every source-level attempt down to 1-2 (VGPR=12/32,
// rounds 2-4), which Little's law shows is exactly the observed ~3 TB/s cap.
__global__ __launch_bounds__(576, 4) void sc_stage1(
    const char* __restrict__ outb, const char* __restrict__ tgtb,
    float* __restrict__ part, int B, int NB)
{
    int tid = threadIdx.x;
    int blk = blockIdx.x;

    float a0 = 0.f, a1 = 0.f, a2 = 0.f, a3 = 0.f, sq = 0.f;

    size_t kstep = (size_t)NB * 9216;        // batch-row stride per k
    const char* ob0 = outb;
    const char* ob1 = outb + kstep;
    const char* ob2 = outb + 2 * kstep;
    const char* ob3 = outb + 3 * kstep;
    const char* tb0 = tgtb;
    const char* tb1 = tgtb + kstep;
    const char* tb2 = tgtb + 2 * kstep;
    const char* tb3 = tgtb + 3 * kstep;

    unsigned voff = (unsigned)blk * 9216u + (unsigned)tid * 16u;
    unsigned vstep = (unsigned)(4 * NB) * 9216u;
    int nfull = B / (4 * NB);                // 4 for B=8192, NB=512

    for (int it = 0; it < nfull; ++it, voff += vstep) {
        f32x4 o0, o1, o2, o3, t0, t1, t2, t3;
        asm volatile(
            "global_load_dwordx4 %0, %[vo], %[so0]\n\t"
            "global_load_dwordx4 %1, %[vo], %[so1]\n\t"
            "global_load_dwordx4 %2, %[vo], %[so2]\n\t"
            "global_load_dwordx4 %3, %[vo], %[so3]\n\t"
            "global_load_dwordx4 %4, %[vo], %[st0]\n\t"
            "global_load_dwordx4 %5, %[vo], %[st1]\n\t"
            "global_load_dwordx4 %6, %[vo], %[st2]\n\t"
            "global_load_dwordx4 %7, %[vo], %[st3]\n\t"
            "s_waitcnt vmcnt(0)"
            : "=v"(o0), "=v"(o1), "=v"(o2), "=v"(o3),
              "=v"(t0), "=v"(t1), "=v"(t2), "=v"(t3)
            : [vo]"v"(voff),
              [so0]"s"(ob0), [so1]"s"(ob1), [so2]"s"(ob2), [so3]"s"(ob3),
              [st0]"s"(tb0), [st1]"s"(tb1), [st2]"s"(tb2), [st3]"s"(tb3));
        float d;
        d = o0[0] - t0[0]; sq = fmaf(d, d, sq); a0 += fabsf(d);
        d = o0[1] - t0[1]; sq = fmaf(d, d, sq); a1 += fabsf(d);
        d = o0[2] - t0[2]; sq = fmaf(d, d, sq); a2 += fabsf(d);
        d = o0[3] - t0[3]; sq = fmaf(d, d, sq); a3 += fabsf(d);
        d = o1[0] - t1[0]; sq = fmaf(d, d, sq); a0 += fabsf(d);
        d = o1[1] - t1[1]; sq = fmaf(d, d, sq); a1 += fabsf(d);
        d = o1[2] - t1[2]; sq = fmaf(d, d, sq); a2 += fabsf(d);
        d = o1[3] - t1[3]; sq = fmaf(d, d, sq); a3 += fabsf(d);
        d = o2[0] - t2[0]; sq = fmaf(d, d, sq); a0 += fabsf(d);
        d = o2[1] - t2[1]; sq = fmaf(d, d, sq); a1 += fabsf(d);
        d = o2[2] - t2[2]; sq = fmaf(d, d, sq); a2 += fabsf(d);
        d = o2[3] - t2[3]; sq = fmaf(d, d, sq); a3 += fabsf(d);
        d = o3[0] - t3[0]; sq = fmaf(d, d, sq); a0 += fabsf(d);
        d = o3[1] - t3[1]; sq = fmaf(d, d, sq); a1 += fabsf(d);
        d = o3[2] - t3[2]; sq = fmaf(d, d, sq); a2 += fabsf(d);
        d = o3[3] - t3[3]; sq = fmaf(d, d, sq); a3 += fabsf(d);
    }
    // tail batches (none for B=8192, NB=512)
    const f32x4* out4 = (const f32x4*)outb;
    const f32x4* tgt4 = (const f32x4*)tgtb;
    for (int b = blk + 4 * nfull * NB; b < B; b += NB) {
        f32x4 o = out4[(size_t)b * HW4 + tid];
        f32x4 t = tgt4[(size_t)b * HW4 + tid];
        float d;
        d = o[0] - t[0]; sq = fmaf(d, d, sq); a0 += fabsf(d);
        d = o[1] - t[1]; sq = fmaf(d, d, sq); a1 += fabsf(d);
        d = o[2] - t[2]; sq = fmaf(d, d, sq); a2 += fabsf(d);
        d = o[3] - t[3]; sq = fmaf(d, d, sq); a3 += fabsf(d);
    }

    float* pbase = part + (size_t)blk * PART_STRIDE;
    ((f32x4*)pbase)[tid] = (f32x4){a0, a1, a2, a3};   // pbase[4*tid+c]

    // block-reduce sq (9 waves)
    #pragma unroll
    for (int off = 32; off; off >>= 1) sq += __shfl_down(sq, off);
    __shared__ float wsum[9];
    int wid = tid >> 6;
    if ((tid & 63) == 0) wsum[wid] = sq;
    __syncthreads();
    if (tid == 0) {
        float s = 0.f;
        #pragma unroll
        for (int w = 0; w < 9; ++w) s += wsum[w];
        pbase[HW] = s;
    }
}

// Stage 2: 36 column blocks x 1024 threads = 64 hw-lanes x 16 row-groups.
// Each thread sums NB/16 rows; 16-way LDS reduce per hw. Block 36 reduces
// the per-block sq partials -> MSE into out[0] (plain store: idempotent
// across graph replays). Proven ~3us in round 2.
__global__ __launch_bounds__(1024) void sc_stage2(
    const float* __restrict__ part, float* __restrict__ A,
    float* __restrict__ out, int NB, int B, float invN)
{
    __shared__ float red[16][64];
    int lane = threadIdx.x & 63;
    int grp  = threadIdx.x >> 6;   // 0..15
    int blk  = blockIdx.x;
    if (blk < 36) {
        int hw = blk * 64 + lane;  // 64 consecutive floats per wave: coalesced
        float s = 0.f;
        for (int r = grp; r < NB; r += 16)
            s += part[(size_t)r * PART_STRIDE + hw];
        red[grp][lane] = s;
        __syncthreads();
        if (grp == 0) {
            float t = 0.f;
            #pragma unroll
            for (int g = 0; g < 16; ++g) t += red[g][lane];
            A[hw] = t / (float)B;
        }
    } else {
        float s = (threadIdx.x < NB)
                    ? part[(size_t)threadIdx.x * PART_STRIDE + HW] : 0.f;
        #pragma unroll
        for (int off = 32; off; off >>= 1) s += __shfl_down(s, off);
        if ((threadIdx.x & 63) == 0) red[0][grp] = s;
        __syncthreads();
        if (threadIdx.x == 0) {
            float t = 0.f;
            #pragma unroll
            for (int g = 0; g < 16; ++g) t += red[0][g];
            out[0] = t * invN;
        }
    }
}

// Stage 3: one block per (i,j): l1 = (A . |psu_ij|)/HW, then
// out += 0.5*mu*l1^2 (54 atomic adds; fp ordering noise ~1e-7 << threshold).
__global__ __launch_bounds__(256) void sc_stage3(
    const float* __restrict__ A, const float* __restrict__ psu,
    const float* __restrict__ mu, float* __restrict__ out)
{
    int j = blockIdx.x;
    int tid = threadIdx.x;
    const float* p = psu + (size_t)j * HW;
    float s = 0.f;
    for (int hw = tid; hw < HW; hw += 256) s += A[hw] * fabsf(p[hw]);
    #pragma unroll
    for (int off = 32; off; off >>= 1) s += __shfl_down(s, off);
    __shared__ float wsum[4];
    if ((tid & 63) == 0) wsum[tid >> 6] = s;
    __syncthreads();
    if (tid == 0) {
        float l1 = (wsum[0] + wsum[1] + wsum[2] + wsum[3]) * (1.0f / HW);
        float contrib = 0.5f * mu[j] * l1 * l1;   // GAMMA = 1
        atomicAdd(out, contrib);
    }
}

extern "C" void kernel_launch(void* const* d_in, const int* in_sizes, int n_in,
                              void* d_out, int out_size, void* d_ws, size_t ws_size,
                              hipStream_t stream)
{
    const float* outp = (const float*)d_in[0];
    const float* tgtp = (const float*)d_in[1];
    const float* psu  = (const float*)d_in[2];
    const float* mu   = (const float*)d_in[3];

    int B   = in_sizes[0] / HW;     // 8192
    int nij = in_sizes[3];          // 54

    int NB = 512;                   // stage-1 blocks; shrink if ws too small
    while (NB > 64 &&
           ((size_t)NB * PART_STRIDE + HW) * sizeof(float) > ws_size)
        NB >>= 1;

    float* part = (float*)d_ws;
    float* A    = part + (size_t)NB * PART_STRIDE;
    float invN  = 1.0f / ((float)B * (float)HW);

    sc_stage1<<<NB, 576, 0, stream>>>((const char*)outp, (const char*)tgtp,
                                      part, B, NB);
    sc_stage2<<<37, 1024, 0, stream>>>(part, A, (float*)d_out, NB, B, invN);
    sc_stage3<<<nij, 256, 0, stream>>>(A, psu, mu, (float*)d_out);
}

// Round 8
// 42.741 us; speedup vs baseline: 2.7835x; 1.0203x over previous
//
#include <hip/hip_runtime.h>

#define HW 2304          // 48*48
#define HW4 576          // HW/4
#define PART_STRIDE 2308 // 2304 A-partials + 1 sq, padded to mult of 4

typedef float __attribute__((ext_vector_type(4))) f32x4;

// Stage 1 (v8): contiguous-slab mapping. Block blk owns batches
// [blk*GB, (blk+1)*GB) -- a contiguous 147KB range of EACH tensor, walked
// sequentially in 4-batch chunks. Rounds 2-7 falsified occupancy (R6: 68%
// occ, worse) and MLP (R7: asm-forced 8 loads in flight, identical perf);
// the surviving theory for the ~3.8TB/s wall is HBM row-buffer thrash from
// the interleaved mapping's ~4096 concurrent 9KB streams. Slabs give each
// block 2 sequential streams (copy-probe-like), maximizing DRAM page hits.
// Per-thread phase stays fixed (tid = one float4 column), so |diff|
// accumulates in 4 registers -- no LDS in the hot loop.
__global__ __launch_bounds__(576, 4) void sc_stage1(
    const f32x4* __restrict__ out4, const f32x4* __restrict__ tgt4,
    float* __restrict__ part, int B, int NB)
{
    int tid = threadIdx.x;
    int blk = blockIdx.x;
    int GB  = (B + NB - 1) / NB;       // batches per block (16 for 8192/512)
    int b0  = blk * GB;
    int bend = min(b0 + GB, B);

    float a0 = 0.f, a1 = 0.f, a2 = 0.f, a3 = 0.f, sq = 0.f;
    size_t base = (size_t)b0 * HW4 + tid;

    int b = b0;
    for (; b + 3 < bend; b += 4, base += 4 * HW4) {
        f32x4 o0 = out4[base];
        f32x4 o1 = out4[base + HW4];
        f32x4 o2 = out4[base + 2 * HW4];
        f32x4 o3 = out4[base + 3 * HW4];
        f32x4 t0 = tgt4[base];
        f32x4 t1 = tgt4[base + HW4];
        f32x4 t2 = tgt4[base + 2 * HW4];
        f32x4 t3 = tgt4[base + 3 * HW4];
        float d;
        d = o0[0] - t0[0]; sq = fmaf(d, d, sq); a0 += fabsf(d);
        d = o0[1] - t0[1]; sq = fmaf(d, d, sq); a1 += fabsf(d);
        d = o0[2] - t0[2]; sq = fmaf(d, d, sq); a2 += fabsf(d);
        d = o0[3] - t0[3]; sq = fmaf(d, d, sq); a3 += fabsf(d);
        d = o1[0] - t1[0]; sq = fmaf(d, d, sq); a0 += fabsf(d);
        d = o1[1] - t1[1]; sq = fmaf(d, d, sq); a1 += fabsf(d);
        d = o1[2] - t1[2]; sq = fmaf(d, d, sq); a2 += fabsf(d);
        d = o1[3] - t1[3]; sq = fmaf(d, d, sq); a3 += fabsf(d);
        d = o2[0] - t2[0]; sq = fmaf(d, d, sq); a0 += fabsf(d);
        d = o2[1] - t2[1]; sq = fmaf(d, d, sq); a1 += fabsf(d);
        d = o2[2] - t2[2]; sq = fmaf(d, d, sq); a2 += fabsf(d);
        d = o2[3] - t2[3]; sq = fmaf(d, d, sq); a3 += fabsf(d);
        d = o3[0] - t3[0]; sq = fmaf(d, d, sq); a0 += fabsf(d);
        d = o3[1] - t3[1]; sq = fmaf(d, d, sq); a1 += fabsf(d);
        d = o3[2] - t3[2]; sq = fmaf(d, d, sq); a2 += fabsf(d);
        d = o3[3] - t3[3]; sq = fmaf(d, d, sq); a3 += fabsf(d);
    }
    for (; b < bend; ++b, base += HW4) {   // tail (empty for B=8192, NB=512)
        f32x4 o = out4[base];
        f32x4 t = tgt4[base];
        float d;
        d = o[0] - t[0]; sq = fmaf(d, d, sq); a0 += fabsf(d);
        d = o[1] - t[1]; sq = fmaf(d, d, sq); a1 += fabsf(d);
        d = o[2] - t[2]; sq = fmaf(d, d, sq); a2 += fabsf(d);
        d = o[3] - t[3]; sq = fmaf(d, d, sq); a3 += fabsf(d);
    }

    float* pbase = part + (size_t)blk * PART_STRIDE;
    ((f32x4*)pbase)[tid] = (f32x4){a0, a1, a2, a3};   // pbase[4*tid+c]

    // block-reduce sq (9 waves)
    #pragma unroll
    for (int off = 32; off; off >>= 1) sq += __shfl_down(sq, off);
    __shared__ float wsum[9];
    int wid = tid >> 6;
    if ((tid & 63) == 0) wsum[wid] = sq;
    __syncthreads();
    if (tid == 0) {
        float s = 0.f;
        #pragma unroll
        for (int w = 0; w < 9; ++w) s += wsum[w];
        pbase[HW] = s;
    }
}

// Stage 2: 36 column blocks x 1024 threads = 64 hw-lanes x 16 row-groups.
// Each thread sums NB/16 rows; 16-way LDS reduce per hw. Block 36 reduces
// the per-block sq partials -> MSE into out[0] (plain store: idempotent
// across graph replays). Proven ~3us in round 2.
__global__ __launch_bounds__(1024) void sc_stage2(
    const float* __restrict__ part, float* __restrict__ A,
    float* __restrict__ out, int NB, int B, float invN)
{
    __shared__ float red[16][64];
    int lane = threadIdx.x & 63;
    int grp  = threadIdx.x >> 6;   // 0..15
    int blk  = blockIdx.x;
    if (blk < 36) {
        int hw = blk * 64 + lane;  // 64 consecutive floats per wave: coalesced
        float s = 0.f;
        for (int r = grp; r < NB; r += 16)
            s += part[(size_t)r * PART_STRIDE + hw];
        red[grp][lane] = s;
        __syncthreads();
        if (grp == 0) {
            float t = 0.f;
            #pragma unroll
            for (int g = 0; g < 16; ++g) t += red[g][lane];
            A[hw] = t / (float)B;
        }
    } else {
        float s = (threadIdx.x < NB)
                    ? part[(size_t)threadIdx.x * PART_STRIDE + HW] : 0.f;
        #pragma unroll
        for (int off = 32; off; off >>= 1) s += __shfl_down(s, off);
        if ((threadIdx.x & 63) == 0) red[0][grp] = s;
        __syncthreads();
        if (threadIdx.x == 0) {
            float t = 0.f;
            #pragma unroll
            for (int g = 0; g < 16; ++g) t += red[0][g];
            out[0] = t * invN;
        }
    }
}

// Stage 3: one block per (i,j): l1 = (A . |psu_ij|)/HW, then
// out += 0.5*mu*l1^2 (54 atomic adds; fp ordering noise ~1e-7 << threshold).
__global__ __launch_bounds__(256) void sc_stage3(
    const float* __restrict__ A, const float* __restrict__ psu,
    const float* __restrict__ mu, float* __restrict__ out)
{
    int j = blockIdx.x;
    int tid = threadIdx.x;
    const float* p = psu + (size_t)j * HW;
    float s = 0.f;
    for (int hw = tid; hw < HW; hw += 256) s += A[hw] * fabsf(p[hw]);
    #pragma unroll
    for (int off = 32; off; off >>= 1) s += __shfl_down(s, off);
    __shared__ float wsum[4];
    if ((tid & 63) == 0) wsum[tid >> 6] = s;
    __syncthreads();
    if (tid == 0) {
        float l1 = (wsum[0] + wsum[1] + wsum[2] + wsum[3]) * (1.0f / HW);
        float contrib = 0.5f * mu[j] * l1 * l1;   // GAMMA = 1
        atomicAdd(out, contrib);
    }
}

extern "C" void kernel_launch(void* const* d_in, const int* in_sizes, int n_in,
                              void* d_out, int out_size, void* d_ws, size_t ws_size,
                              hipStream_t stream)
{
    const float* outp = (const float*)d_in[0];
    const float* tgtp = (const float*)d_in[1];
    const float* psu  = (const float*)d_in[2];
    const float* mu   = (const float*)d_in[3];

    int B   = in_sizes[0] / HW;     // 8192
    int nij = in_sizes[3];          // 54

    int NB = 512;                   // stage-1 blocks; shrink if ws too small
    while (NB > 64 &&
           ((size_t)NB * PART_STRIDE + HW) * sizeof(float) > ws_size)
        NB >>= 1;

    float* part = (float*)d_ws;
    float* A    = part + (size_t)NB * PART_STRIDE;
    float invN  = 1.0f / ((float)B * (float)HW);

    sc_stage1<<<NB, 576, 0, stream>>>((const f32x4*)outp, (const f32x4*)tgtp,
                                      part, B, NB);
    sc_stage2<<<37, 1024, 0, stream>>>(part, A, (float*)d_out, NB, B, invN);
    sc_stage3<<<nij, 256, 0, stream>>>(A, psu, mu, (float*)d_out);
}